// Round 1
// baseline (4460.495 us; speedup 1.0000x reference)
//
#include <hip/hip_runtime.h>
#include <hip/hip_bf16.h>
#include <stdint.h>

#define VOCAB 50257
#define VPAD  50304
#define DEMB  512
#define RES   2048
#define ROUT  512
#define BB    8
#define TT    256
#define BT    2048
#define SLOTS 80
#define NCAP  8192   // chunk capacity; each chunk = 16 nnz of ONE row (padded)
#define NREG  8      // register-resident chunks per thread (8*512 = 4096 chunks)

typedef _Float16 half8 __attribute__((ext_vector_type(8)));
typedef _Float16 h4v   __attribute__((ext_vector_type(4)));
typedef float f32x4 __attribute__((ext_vector_type(4)));

// async global->LDS, 16B per lane; LDS dest is wave-uniform base + lane*16
__device__ __forceinline__ void g2lds16(const _Float16* g, _Float16* l) {
  __builtin_amdgcn_global_load_lds((const __attribute__((address_space(1))) void*)g,
                                   (__attribute__((address_space(3))) void*)l,
                                   16, 0, 0);
}

// ---------------- prep: casts / gather / transpose ----------------
__global__ __launch_bounds__(256)
void prep_k(const int* __restrict__ x, const float* __restrict__ temb,
            const float* __restrict__ Win, const float* __restrict__ Wb,
            const float* __restrict__ Wa,
            _Float16* __restrict__ Aemb, _Float16* __restrict__ Wt,
            _Float16* __restrict__ Wb16, _Float16* __restrict__ Wa16) {
  const int gt = blockIdx.x * 256 + threadIdx.x;
  const int gs = gridDim.x * 256;
  for (int i = gt; i < BT * DEMB; i += gs) {
    int bt = i >> 9, d = i & 511;
    Aemb[i] = (_Float16)temb[(size_t)x[bt] * DEMB + d];
  }
  for (int i = gt; i < RES * DEMB; i += gs) {   // Wt[r][d] = Win[d][r]
    int rr = i >> 9, d = i & 511;
    Wt[i] = (_Float16)Win[(size_t)d * RES + rr];
  }
  for (int i = gt; i < ROUT * RES; i += gs) Wb16[i] = (_Float16)Wb[i];
  for (int i = gt; i < VPAD * ROUT; i += gs)
    Wa16[i] = (i < VOCAB * ROUT) ? (_Float16)Wa[i] : (_Float16)0.f;
}

// ---------------- build ELL of W_rec (block per row, ballot compaction) ----------------
__global__ __launch_bounds__(256)
void build_ell_k(const float* __restrict__ Wrec, float* __restrict__ evals,
                 unsigned short* __restrict__ ecols, int* __restrict__ ecnt) {
  __shared__ int base;
  const int r = blockIdx.x;
  if (threadIdx.x == 0) base = 0;
  __syncthreads();
  const float* row = Wrec + (size_t)r * RES;
  const int lane = threadIdx.x & 63;
  for (int j0 = 0; j0 < RES; j0 += 256) {
    int j = j0 + threadIdx.x;
    float v = row[j];
    bool nz = (v != 0.f);
    unsigned long long mask = __ballot(nz);
    int pre = __popcll(mask & ((1ull << lane) - 1ull));
    int tot = __popcll(mask);
    int wb = 0;
    if (lane == 0 && tot) wb = atomicAdd(&base, tot);
    wb = __shfl(wb, 0);
    if (nz) {
      int slot = wb + pre;
      if (slot < SLOTS) {
        evals[(size_t)r * SLOTS + slot] = v;
        ecols[(size_t)r * SLOTS + slot] = (unsigned short)j;
      }
    }
  }
  __syncthreads();
  if (threadIdx.x == 0) ecnt[r] = (base <= SLOTS) ? base : SLOTS;
}

// ---------------- chunkify: ELL rows -> 16-slot single-row chunks (slot-major) ----------------
// ckval[j][c] = fp32 value of slot j of chunk c; ckcolp[p][c] packs byte-offsets of
// slots 2p / 2p+1 (col*2, lo|hi<<16); ckrow[c] = row*4 (byte offset into rowbuf).
__global__ __launch_bounds__(256)
void chunkify_k(const float* __restrict__ evals, const unsigned short* __restrict__ ecols,
                const int* __restrict__ ecnt, float* __restrict__ ckval,
                unsigned int* __restrict__ ckcolp, unsigned short* __restrict__ ckrow,
                int* __restrict__ ncnt) {
  const int r = blockIdx.x * 256 + threadIdx.x;
  if (r >= RES) return;
  const int cnt = ecnt[r];
  const int nc = (cnt + 15) >> 4;
  if (nc == 0) return;
  const int base = atomicAdd(ncnt, nc);
  for (int c = 0; c < nc; ++c) {
    const int cc = base + c;
    if (cc >= NCAP) break;                 // safety (statistically impossible)
    ckrow[cc] = (unsigned short)(r * 4);
    unsigned int lo = 0;
    for (int j = 0; j < 16; ++j) {
      const int idx = c * 16 + j;
      float v = 0.f; unsigned int c2 = 0;
      if (idx < cnt) {
        v  = evals[(size_t)r * SLOTS + idx];
        c2 = (unsigned int)ecols[(size_t)r * SLOTS + idx] * 2u;
      }
      ckval[(size_t)j * NCAP + cc] = v;
      if ((j & 1) == 0) lo = c2;
      else ckcolp[(size_t)(j >> 1) * NCAP + cc] = lo | (c2 << 16);
    }
  }
}

// ---------------- sync-free per-batch recurrence: 8 blocks, W register-resident ----------------
__global__ __launch_bounds__(512, 2)
void rec2_k(const float* __restrict__ ep, const float* __restrict__ ckval,
            const unsigned int* __restrict__ ckcolp, const unsigned short* __restrict__ ckrow,
            const int* __restrict__ ncnt, const float* __restrict__ a,
            const float* __restrict__ h0, _Float16* __restrict__ hs) {
  __shared__ __align__(16) _Float16 h16[RES];    // current h (this batch), 4 KB, LDS offset 0
  __shared__ __align__(16) float rowbuf[RES];    // per-row accumulators, 8 KB
  const int tid = threadIdx.x;
  const int bb  = blockIdx.x;                    // batch
  const int NC  = *ncnt;

  // ---- load W chunks into registers (one-time) ----
  float        wv[NREG * 16];
  unsigned int wc[NREG * 8];
  int          rowoff[NREG];
  #pragma unroll
  for (int s = 0; s < NREG; ++s) {
    const int c = s * 512 + tid;
    const bool ok = (c < NC);
    rowoff[s] = ok ? (int)ckrow[c] : 0;
    #pragma unroll
    for (int j = 0; j < 16; ++j)
      wv[s * 16 + j] = ok ? ckval[(size_t)j * NCAP + c] : 0.f;
    #pragma unroll
    for (int p = 0; p < 8; ++p)
      wc[s * 8 + p] = ok ? ckcolp[(size_t)p * NCAP + c] : 0u;
  }

  // ---- init state: 4 units per thread ----
  const int u0 = tid * 4;
  float hown[4], au[4];
  {
    const f32x4 hv = *(const f32x4*)(h0 + u0);
    const f32x4 av = *(const f32x4*)(a + u0);
    h4v hi;
    #pragma unroll
    for (int q = 0; q < 4; ++q) { hown[q] = hv[q]; au[q] = av[q]; hi[q] = (_Float16)hv[q]; }
    *(h4v*)(h16 + u0) = hi;
    *(f32x4*)(rowbuf + u0) = (f32x4){0.f, 0.f, 0.f, 0.f};
  }
  __syncthreads();

  const float*    epp = ep + (size_t)bb * TT * RES + u0;
  _Float16*       hsp = hs + (size_t)bb * TT * RES + u0;

  for (int t = 0; t < TT; ++t) {
    const f32x4 epv = *(const f32x4*)epp;        // prefetch, consumed after barrier

    // ---- gather: register-resident chunks ----
    #pragma unroll
    for (int s = 0; s < NREG; ++s) {
      float a0 = 0.f, a1 = 0.f, a2 = 0.f, a3 = 0.f;
      #pragma unroll
      for (int p = 0; p < 8; ++p) {
        const unsigned int w = wc[s * 8 + p];
        const _Float16 hA = *(const _Float16*)((const char*)h16 + (w & 0xffffu));
        const _Float16 hB = *(const _Float16*)((const char*)h16 + (w >> 16));
        if ((p & 1) == 0) {
          a0 = fmaf(wv[s * 16 + 2 * p],     (float)hA, a0);
          a1 = fmaf(wv[s * 16 + 2 * p + 1], (float)hB, a1);
        } else {
          a2 = fmaf(wv[s * 16 + 2 * p],     (float)hA, a2);
          a3 = fmaf(wv[s * 16 + 2 * p + 1], (float)hB, a3);
        }
      }
      const float fs = (a0 + a1) + (a2 + a3);
      if (fs != 0.f) atomicAdd((float*)((char*)rowbuf + rowoff[s]), fs);
    }
    // ---- gather: overflow chunks streamed from L2 (~0-2 per thread) ----
    for (int c = NREG * 512 + tid; c < NC; c += 512) {
      const int ro = (int)ckrow[c];
      float b0 = 0.f, b1 = 0.f;
      #pragma unroll
      for (int p = 0; p < 8; ++p) {
        const unsigned int w = ckcolp[(size_t)p * NCAP + c];
        const float v0 = ckval[(size_t)(2 * p) * NCAP + c];
        const float v1 = ckval[(size_t)(2 * p + 1) * NCAP + c];
        const _Float16 hA = *(const _Float16*)((const char*)h16 + (w & 0xffffu));
        const _Float16 hB = *(const _Float16*)((const char*)h16 + (w >> 16));
        b0 = fmaf(v0, (float)hA, b0);
        b1 = fmaf(v1, (float)hB, b1);
      }
      const float fs = b0 + b1;
      if (fs != 0.f) atomicAdd((float*)((char*)rowbuf + ro), fs);
    }
    __syncthreads();

    // ---- update: 4 units/thread ----
    const f32x4 rs = *(f32x4*)(rowbuf + u0);
    *(f32x4*)(rowbuf + u0) = (f32x4){0.f, 0.f, 0.f, 0.f};   // re-zero for next step
    h4v ho;
    #pragma unroll
    for (int q = 0; q < 4; ++q) {
      float pre = epv[q] + rs[q];
      pre = fminf(10.f, fmaxf(-10.f, pre));
      const float z  = __expf(2.f * pre);
      const float th = __fdividef(z - 1.f, z + 1.f);          // tanh(pre), err ~1e-7
      const float hn = fmaf(au[q], th - hown[q], hown[q]);    // (1-a)h + a*tanh
      hown[q] = hn;
      ho[q] = (_Float16)hn;
    }
    *(h4v*)(h16 + u0) = ho;      // h for next step
    *(h4v*)hsp = ho;             // hs[b][t][u0..u0+3]
    __syncthreads();
    epp += RES; hsp += RES;
  }
}

// ---------------- f16 MFMA GEMM: C[M,N] = A[M,K] @ B^T (B stored [N][K]) ----------------
// MODE 0: f32 out; MODE 1: f32 out + bias + col<Ncheck guard; MODE 2: f16 out
template <int MODE>
__global__ __launch_bounds__(256)
void gemm_bt(const _Float16* __restrict__ A, const _Float16* __restrict__ B,
             float* __restrict__ Cf, _Float16* __restrict__ Ch,
             const float* __restrict__ bias, int Nld, int Ncheck, int K) {
  __shared__ __align__(16) _Float16 sA[128 * 64];
  __shared__ __align__(16) _Float16 sB[128 * 64];
  const int tid = threadIdx.x;
  const int m0 = blockIdx.x * 128, n0 = blockIdx.y * 128;
  const int lane = tid & 63, w = tid >> 6;
  const int wm = (w & 1) << 6, wn = (w >> 1) << 6;
  const int lrow = lane & 15, quad = lane >> 4;

  f32x4 acc[4][4];
  #pragma unroll
  for (int i = 0; i < 4; ++i)
    #pragma unroll
    for (int j = 0; j < 4; ++j) acc[i][j] = (f32x4){0.f, 0.f, 0.f, 0.f};

  const _Float16* Ab = A + (size_t)m0 * K;
  const _Float16* Bb = B + (size_t)n0 * K;
  const int kt_n = K >> 6;
  for (int kt = 0; kt < kt_n; ++kt) {
    const int k0 = kt << 6;
    // stage 128x64 A and B tiles; k8 group XOR-swizzled by row for conflict-free ds_read_b128
    #pragma unroll
    for (int r = 0; r < 4; ++r) {
      int s = (r << 8) + tid;                 // group index 0..1023
      int row = s >> 3;
      int k8 = (s & 7) ^ (row & 7);
      g2lds16(Ab + (size_t)row * K + k0 + (k8 << 3), sA + ((s & ~63) << 3));
      g2lds16(Bb + (size_t)row * K + k0 + (k8 << 3), sB + ((s & ~63) << 3));
    }
    __syncthreads();
    #pragma unroll
    for (int kk = 0; kk < 2; ++kk) {
      half8 af[4], bf[4];
      #pragma unroll
      for (int i = 0; i < 4; ++i) {
        int ra = wm + (i << 4) + lrow;
        af[i] = *(const half8*)(sA + (((ra << 3) + (((kk << 2) + quad) ^ (ra & 7))) << 3));
        int rb = wn + (i << 4) + lrow;
        bf[i] = *(const half8*)(sB + (((rb << 3) + (((kk << 2) + quad) ^ (rb & 7))) << 3));
      }
      #pragma unroll
      for (int i = 0; i < 4; ++i)
        #pragma unroll
        for (int j = 0; j < 4; ++j)
          acc[i][j] = __builtin_amdgcn_mfma_f32_16x16x32_f16(af[i], bf[j], acc[i][j], 0, 0, 0);
    }
    __syncthreads();
  }
  #pragma unroll
  for (int i = 0; i < 4; ++i) {
    const int row = m0 + wm + (i << 4) + (quad << 2);
    #pragma unroll
    for (int j = 0; j < 4; ++j) {
      const int col = n0 + wn + (j << 4) + lrow;
      f32x4 v = acc[i][j];
      if (MODE == 1) {
        if (col < Ncheck) {
          const float bv = bias[col];
          #pragma unroll
          for (int r2 = 0; r2 < 4; ++r2)
            Cf[(size_t)(row + r2) * Nld + col] = v[r2] + bv;
        }
      } else if (MODE == 0) {
        #pragma unroll
        for (int r2 = 0; r2 < 4; ++r2) Cf[(size_t)(row + r2) * Nld + col] = v[r2];
      } else {
        #pragma unroll
        for (int r2 = 0; r2 < 4; ++r2) Ch[(size_t)(row + r2) * Nld + col] = (_Float16)v[r2];
      }
    }
  }
}

extern "C" void kernel_launch(void* const* d_in, const int* in_sizes, int n_in,
                              void* d_out, int out_size, void* d_ws, size_t ws_size,
                              hipStream_t stream) {
  const int*   x    = (const int*)d_in[0];
  const float* temb = (const float*)d_in[1];
  const float* Win  = (const float*)d_in[2];
  const float* Wrec = (const float*)d_in[3];
  const float* a    = (const float*)d_in[4];
  const float* Wb   = (const float*)d_in[5];
  const float* Wa   = (const float*)d_in[6];
  const float* bias = (const float*)d_in[7];
  const float* h0   = (const float*)d_in[8];
  float* out = (float*)d_out;
  (void)in_sizes; (void)n_in; (void)out_size; (void)ws_size;

  char* p = (char*)d_ws;
  auto take = [&](size_t bytes) -> char* {
    char* r = p;
    p += (bytes + 255) & ~(size_t)255;
    return r;
  };
  _Float16* Aemb = (_Float16*)take((size_t)BT * DEMB * 2);
  _Float16* Wt   = (_Float16*)take((size_t)RES * DEMB * 2);
  _Float16* Wb16 = (_Float16*)take((size_t)ROUT * RES * 2);
  _Float16* Wa16 = (_Float16*)take((size_t)VPAD * ROUT * 2);
  _Float16* proj = (_Float16*)take((size_t)BT * ROUT * 2);
  float*    ep   = (float*)   take((size_t)BT * RES * 4);
  _Float16* hs   = (_Float16*)take((size_t)BT * RES * 2);
  float*    evals= (float*)   take((size_t)RES * SLOTS * 4);
  unsigned short* ecols = (unsigned short*)take((size_t)RES * SLOTS * 2);
  int*      ecnt = (int*)take((size_t)RES * 4);
  int*      ncnt = (int*)take(256);
  float*    ckval = (float*)take((size_t)16 * NCAP * 4);
  unsigned int* ckcolp = (unsigned int*)take((size_t)8 * NCAP * 4);
  unsigned short* ckrow = (unsigned short*)take((size_t)NCAP * 2);

  hipMemsetAsync(ncnt, 0, sizeof(int), stream);
  prep_k<<<dim3(2048), 256, 0, stream>>>(x, temb, Win, Wb, Wa, Aemb, Wt, Wb16, Wa16);
  build_ell_k<<<dim3(RES), 256, 0, stream>>>(Wrec, evals, ecols, ecnt);
  chunkify_k<<<dim3(RES / 256), 256, 0, stream>>>(evals, ecols, ecnt, ckval, ckcolp, ckrow, ncnt);
  // ep = Aemb @ Wt^T   (M=2048, N=2048, K=512)
  gemm_bt<0><<<dim3(16, 16), 256, 0, stream>>>(Aemb, Wt, ep, nullptr, nullptr, RES, RES, DEMB);
  // sync-free per-batch recurrence (8 blocks, one per batch)
  rec2_k<<<dim3(BB), 512, 0, stream>>>(ep, ckval, ckcolp, ckrow, ncnt, a, h0, hs);
  // proj = hs @ Wb16^T (M=2048, N=512, K=2048), f16 out
  gemm_bt<2><<<dim3(16, 4), 256, 0, stream>>>(hs, Wb16, nullptr, proj, nullptr, ROUT, ROUT, RES);
  // logits = proj @ Wa16^T + bias (M=2048, N=50304->50257, K=512)
  gemm_bt<1><<<dim3(16, 393), 256, 0, stream>>>(proj, Wa16, out, nullptr, bias, VOCAB, VOCAB, ROUT);
}